// Round 4
// baseline (421.788 us; speedup 1.0000x reference)
//
#include <hip/hip_runtime.h>
#include <stdint.h>

typedef int v4i  __attribute__((ext_vector_type(4)));
typedef int v16i __attribute__((ext_vector_type(16)));

// ---------------- kernel 1: max |tanh(w)| over all 3*3*256*256 weights ----------------
__global__ void k_wmax(const float* __restrict__ w, unsigned* __restrict__ maxbits, int n) {
    int i = blockIdx.x * blockDim.x + threadIdx.x;
    int stride = gridDim.x * blockDim.x;
    float m = 0.f;
    for (; i < n; i += stride) m = fmaxf(m, fabsf(tanhf(w[i])));
#pragma unroll
    for (int off = 32; off > 0; off >>= 1)
        m = fmaxf(m, __shfl_xor(m, off, 64));
    if ((threadIdx.x & 63) == 0) atomicMax(maxbits, __float_as_uint(m));
}

// ---------------- kernel 2: quantize weights -> int8 {-3,-1,1,3}, layout [co][tap*256+ci] ----
__global__ void k_wq(const float* __restrict__ w, const unsigned* __restrict__ maxbits,
                     int8_t* __restrict__ wqt) {
    int t = blockIdx.x * 256 + threadIdx.x;   // 36864 threads
    int co = t & 255;
    int kblk = t >> 8;                        // 0..143, 16 k-values each
    float inv = 0.5f / __uint_as_float(*maxbits);
    int8_t b[16];
#pragma unroll
    for (int i = 0; i < 16; ++i) {
        float tv = tanhf(w[(long)(kblk * 16 + i) * 256 + co]);   // HWIO [k][co]
        int qi = (int)rintf((tv * inv + 0.5f) * 3.0f);           // 0..3, half-even = jnp.round
        b[i] = (int8_t)(2 * qi - 3);                             // {-3,-1,1,3}
    }
    *(int4*)(wqt + (long)co * 2304 + kblk * 16) = *(int4*)b;
}

// ---------------- kernel 3: quantize acts -> int8 {0..3} into zero-padded [32][58][58][256] ---
__global__ void k_xq(const float* __restrict__ x, int8_t* __restrict__ xqp) {
    int t = blockIdx.x * 256 + threadIdx.x;   // 32*58*58*16 threads, 16 bytes each
    int g  = t & 15;
    int p  = t >> 4;
    int xp = p % 58;
    int q  = p / 58;
    int yp = q % 58;
    int n  = q / 58;
    int4 r;
    if (yp == 0 || yp == 57 || xp == 0 || xp == 57) {
        r = make_int4(0, 0, 0, 0);
    } else {
        const float4* px = (const float4*)(x + (((long)((n * 56 + (yp - 1)) * 56 + (xp - 1))) << 8) + g * 16);
        int wds[4];
#pragma unroll
        for (int jj = 0; jj < 4; ++jj) {
            float4 v = px[jj];
            int b0 = (int)rintf(fminf(fmaxf(v.x, 0.f), 1.f) * 3.f);
            int b1 = (int)rintf(fminf(fmaxf(v.y, 0.f), 1.f) * 3.f);
            int b2 = (int)rintf(fminf(fmaxf(v.z, 0.f), 1.f) * 3.f);
            int b3 = (int)rintf(fminf(fmaxf(v.w, 0.f), 1.f) * 3.f);
            wds[jj] = b0 | (b1 << 8) | (b2 << 16) | (b3 << 24);
        }
        r = make_int4(wds[0], wds[1], wds[2], wds[3]);
    }
    *(int4*)(xqp + ((long)t << 4)) = r;
}

// ---------------- kernel 4: register-direct implicit-GEMM conv, i8 MFMA 32x32x32 ------------
// NO LDS, NO barriers. A-fragment for mfma_i32_32x32x32_i8 is 16 contiguous bytes of one
// M-row (row=lane&31, off=(lane>>5)*16 + kk*32) -> load straight from the padded xqp with
// global_load_dwordx4. Same for B from wqt[co][k]. Fully-unrolled 288-load/288-MFMA body:
// compiler software-pipelines with fine-grained vmcnt, every wave independent. Sequential
// kk-chunks (32B steps through 128B lines) give 3/4 L1 hits; wave pairs share rows/cols.
#define BM 128
#define BN 128

__global__ __launch_bounds__(256, 3) void k_conv(const int8_t* __restrict__ xqp,
                                                 const int8_t* __restrict__ wqt,
                                                 float* __restrict__ out) {
    const int tid    = threadIdx.x;
    const int wv     = tid >> 6;
    const int lane   = tid & 63;
    const int mBase  = blockIdx.x * BM;
    const int coBase = blockIdx.y * BN;
    const int wm  = (wv & 1) * 64;
    const int wn  = (wv >> 1) * 64;
    const int l31 = lane & 31;
    const int hi  = lane >> 5;

    // per-lane fragment base pointers (center tap, kk=0)
    const int8_t* aR[2];
    const int8_t* bC[2];
#pragma unroll
    for (int t = 0; t < 2; ++t) {
        int m = mBase + wm + t * 32 + l31;
        int n = m / 3136;
        int rem = m - n * 3136;
        int y = rem / 56;
        int x = rem - y * 56;
        aR[t] = xqp + (((long)((n * 58 + y) * 58 + x)) << 8) + hi * 16;
        int c = coBase + wn + t * 32 + l31;
        bC[t] = wqt + (long)c * 2304 + hi * 16;
    }

    v16i acc[2][2];
#pragma unroll
    for (int a = 0; a < 2; ++a)
#pragma unroll
        for (int b = 0; b < 2; ++b)
#pragma unroll
            for (int r = 0; r < 16; ++r) acc[a][b][r] = 0;

#pragma unroll
    for (int ky = 0; ky < 3; ++ky) {
#pragma unroll
        for (int kx = 0; kx < 3; ++kx) {
            const int aOff = (ky * 58 + kx) << 8;      // spatial shift in padded xqp
            const int bOff = (ky * 3 + kx) << 8;       // tap*256 in wqt row
#pragma unroll
            for (int kk = 0; kk < 8; ++kk) {
                const int ko = kk * 32;
                v4i a0 = *(const v4i*)(aR[0] + aOff + ko);
                v4i a1 = *(const v4i*)(aR[1] + aOff + ko);
                v4i b0 = *(const v4i*)(bC[0] + bOff + ko);
                v4i b1 = *(const v4i*)(bC[1] + bOff + ko);
                acc[0][0] = __builtin_amdgcn_mfma_i32_32x32x32_i8(a0, b0, acc[0][0], 0, 0, 0);
                acc[0][1] = __builtin_amdgcn_mfma_i32_32x32x32_i8(a0, b1, acc[0][1], 0, 0, 0);
                acc[1][0] = __builtin_amdgcn_mfma_i32_32x32x32_i8(a1, b0, acc[1][0], 0, 0, 0);
                acc[1][1] = __builtin_amdgcn_mfma_i32_32x32x32_i8(a1, b1, acc[1][1], 0, 0, 0);
            }
        }
    }

    // epilogue: 32x32 C/D layout col=lane&31, row=(reg&3)+8*(reg>>2)+4*(lane>>5); out = acc/9
    const float s = 1.0f / 9.0f;
#pragma unroll
    for (int mt = 0; mt < 2; ++mt) {
#pragma unroll
        for (int nt = 0; nt < 2; ++nt) {
            const int ocol = coBase + wn + nt * 32 + l31;
#pragma unroll
            for (int reg = 0; reg < 16; ++reg) {
                const int row = (reg & 3) + 8 * (reg >> 2) + 4 * hi;
                const long orow = mBase + wm + mt * 32 + row;
                out[orow * 256 + ocol] = (float)acc[mt][nt][reg] * s;
            }
        }
    }
}

extern "C" void kernel_launch(void* const* d_in, const int* in_sizes, int n_in,
                              void* d_out, int out_size, void* d_ws, size_t ws_size,
                              hipStream_t stream) {
    const float* x = (const float*)d_in[0];   // (32,56,56,256) NHWC fp32
    const float* w = (const float*)d_in[1];   // (3,3,256,256) HWIO fp32
    float* out = (float*)d_out;               // (32,56,56,256) fp32

    unsigned* maxbits = (unsigned*)d_ws;
    int8_t* wqt = (int8_t*)d_ws + 4096;              // 2304*256 = 589824 B, [co][k]
    int8_t* xqp = (int8_t*)d_ws + 4096 + 589824;     // 32*58*58*256 = 27,557,888 B

    hipMemsetAsync(maxbits, 0, 4, stream);           // ws poisoned 0xAA -> zero for atomicMax
    k_wmax<<<256, 256, 0, stream>>>(w, maxbits, 3 * 3 * 256 * 256);
    k_wq<<<144, 256, 0, stream>>>(w, maxbits, wqt);
    k_xq<<<6728, 256, 0, stream>>>(x, xqp);          // 32*58*58*16 threads
    dim3 grid(784, 2);                               // 100352/128 x 256/128
    k_conv<<<grid, 256, 0, stream>>>(xqp, wqt, out);
}